// Round 6
// baseline (31188.937 us; speedup 1.0000x reference)
//
#include <hip/hip_runtime.h>
#include <math.h>

#define BM 128
#define BN 128
#define EPSV 1e-12f
#define NEG_INF_V -1000000000.0f
#define NBINS 2048
#define FBINS 1024
#define FSCALE 5120.0f
#define SCAP 2048
#define CAP 2048
#define SSCAP 1024
#define TAU 0.10f

typedef __attribute__((ext_vector_type(8))) short bf16x8;
typedef __attribute__((ext_vector_type(4))) float f32x4;

__device__ __forceinline__ unsigned short f2bf(float f) {
    unsigned int u = __float_as_uint(f);
    unsigned int r = (u + 0x7fffu + ((u >> 16) & 1u)) >> 16;
    return (unsigned short)r;
}
__device__ __forceinline__ float bf2f(unsigned short h) {
    return __uint_as_float(((unsigned int)h) << 16);
}
__device__ __forceinline__ void split3(float v, unsigned short& h0,
                                       unsigned short& h1, unsigned short& h2) {
    h0 = f2bf(v); float r = v - bf2f(h0);
    h1 = f2bf(r); r -= bf2f(h1);
    h2 = f2bf(r);
}
__device__ __forceinline__ void gload_lds16(const unsigned short* g, const unsigned short* l) {
    __builtin_amdgcn_global_load_lds((const __attribute__((address_space(1))) void*)g,
                                     (__attribute__((address_space(3))) void*)l, 16, 0, 0);
}

// ------- fused: normalize x rows + split into 3 bf16 planes (one wave per row) -------
__global__ void xnsplit_kernel(const float* __restrict__ x, float* __restrict__ xn,
                               unsigned short* __restrict__ Xs, size_t xplane, int D) {
    int row = blockIdx.x;
    int lane = threadIdx.x;
    const float4* xr = (const float4*)(x + (size_t)row * D);
    float4* xo = (float4*)(xn + (size_t)row * D);
    int per = (D / 4) / 64;          // D=512 -> 2
    float ss = 0.f;
    float4 v[2];
    for (int i = 0; i < per; ++i) {
        float4 t = xr[lane * per + i];
        v[i] = t;
        ss += t.x * t.x + t.y * t.y + t.z * t.z + t.w * t.w;
    }
    for (int off = 32; off >= 1; off >>= 1) ss += __shfl_xor(ss, off);
    float denom = fmaxf(sqrtf(ss), EPSV);
    float vals[8];
    for (int i = 0; i < per; ++i) {
        float4 t = v[i];
        t.x /= denom; t.y /= denom; t.z /= denom; t.w /= denom;
        xo[lane * per + i] = t;
        vals[i * 4 + 0] = t.x; vals[i * 4 + 1] = t.y;
        vals[i * 4 + 2] = t.z; vals[i * 4 + 3] = t.w;
    }
    unsigned short h0[8], h1[8], h2[8];
#pragma unroll
    for (int i = 0; i < 8; ++i) split3(vals[i], h0[i], h1[i], h2[i]);
    size_t off0 = (size_t)row * D + lane * 8;
    *(bf16x8*)(Xs + off0)              = *(bf16x8*)h0;
    *(bf16x8*)(Xs + xplane + off0)     = *(bf16x8*)h1;
    *(bf16x8*)(Xs + 2 * xplane + off0) = *(bf16x8*)h2;
}

// ---------------- key inverse norms (one wave per key row) ----------------
__global__ void kinv_kernel(const float* __restrict__ keys, float* __restrict__ kinv,
                            int M, int D) {
    int wave = threadIdx.x >> 6;
    int lane = threadIdx.x & 63;
    int row = blockIdx.x * 4 + wave;
    if (row >= M) return;
    const float4* kr = (const float4*)(keys + (size_t)row * D);
    int per = (D / 4) / 64;
    float ss = 0.f;
    for (int i = 0; i < per; ++i) {
        float4 t = kr[lane * per + i];
        ss += t.x * t.x + t.y * t.y + t.z * t.z + t.w * t.w;
    }
    for (int off = 32; off >= 1; off >>= 1) ss += __shfl_xor(ss, off);
    if (lane == 0) kinv[row] = 1.0f / fmaxf(sqrtf(ss), EPSV);
}

// ------- split keys*kinv into 3 bf16 planes, packed per (col-tile, k-chunk) in
// ------- fragment order with XOR bank swizzle ----------
__global__ __launch_bounds__(256)
void ksplit_kernel(const float* __restrict__ keys, const float* __restrict__ kinv,
                   unsigned short* __restrict__ K0, unsigned short* __restrict__ K1,
                   unsigned short* __restrict__ K2, int M, int D, int nk) {
    const int ct = blockIdx.x / nk;
    const int t  = blockIdx.x % nk;
    const size_t blk = (size_t)blockIdx.x * 4096;   // shorts
#pragma unroll
    for (int half = 0; half < 2; ++half) {
        int sig = half * 256 + threadIdx.x;         // slot 0..511
        int tau = sig >> 6;
        int mp  = (sig >> 2) & 15;
        int qp  = sig & 3;
        int row = ct * 128 + tau * 16 + mp;
        int qs  = qp ^ (mp & 3);
        unsigned short h0[8], h1[8], h2[8];
        if (row < M) {
            float inv = kinv[row];
            const float* src = keys + (size_t)row * D + t * 32 + qs * 8;
#pragma unroll
            for (int i = 0; i < 8; ++i) split3(src[i] * inv, h0[i], h1[i], h2[i]);
        } else {
#pragma unroll
            for (int i = 0; i < 8; ++i) { h0[i] = 0; h1[i] = 0; h2[i] = 0; }
        }
        size_t off = blk + (size_t)sig * 8;
        *(bf16x8*)(K0 + off) = *(bf16x8*)h0;
        *(bf16x8*)(K1 + off) = *(bf16x8*)h1;
        *(bf16x8*)(K2 + off) = *(bf16x8*)h2;
    }
}

// ---------------- MFMA GEMM: 128x128 block, 4 waves 2x2, 6 split-products ----------------
// 3 blocks/CU (LDS 48KB, VGPR<=170). Product order sb=2,1,0 with plane-2 A last.
__global__ __launch_bounds__(256, 3)
void gemm_kernel(const unsigned short* __restrict__ Xs,   // 3 planes, stride xplane
                 const unsigned short* __restrict__ Kp,   // 3 packed planes, stride kplane
                 const int* __restrict__ values,
                 int2* __restrict__ cand, int* __restrict__ cnt,
                 int M, int D, int nk, size_t xplane, size_t kplane) {
    __shared__ unsigned short Bs[2][3 * 4096];   // 2 x 24 KB

    const int tid  = threadIdx.x;
    const int lane = tid & 63;
    const int w    = tid >> 6;
    const int wx   = w >> 1, wy = w & 1;
    const int rt   = blockIdx.x;
    const int ct   = blockIdx.y;
    const int row0 = rt * BM, col0 = ct * BN;
    const int mq   = lane & 15;
    const int qd   = lane >> 4;
    const int bswz = mq * 32 + ((qd ^ (mq & 3)) << 3);

    f32x4 acc[4][4];
#pragma unroll
    for (int i = 0; i < 4; ++i)
#pragma unroll
        for (int j = 0; j < 4; ++j) acc[i][j] = (f32x4){0.f, 0.f, 0.f, 0.f};

#define STAGE(t_, buf_)                                                          \
    {                                                                            \
        const size_t blk_ = ((size_t)ct * nk + (t_)) * 4096;                     \
        _Pragma("unroll")                                                        \
        for (int i_ = 0; i_ < 6; ++i_) {                                         \
            int s_ = w + i_ * 4;                                                 \
            int sp_ = s_ >> 3, pt_ = s_ & 7;                                     \
            gload_lds16(Kp + (size_t)sp_ * kplane + blk_ + pt_ * 512 + lane * 8, \
                        &Bs[buf_][sp_ * 4096 + pt_ * 512]);                      \
        }                                                                        \
    }

    STAGE(0, 0);

    const unsigned short* arow_base = Xs + (size_t)(row0 + wx * 64 + mq) * D + qd * 8;

    for (int t = 0; t < nk; ++t) {
        const int buf = t & 1;
        __syncthreads();                          // Bs[buf] staged; drains in-flight loads

        if (t + 1 < nk) STAGE(t + 1, buf ^ 1);    // longest-latency first: full chunk of slack

        // A fragments, issued in use order (plane 0 first, plane 2 last-used)
        bf16x8 af[3][4];
#pragma unroll
        for (int s = 0; s < 3; ++s)
#pragma unroll
            for (int ta = 0; ta < 4; ++ta)
                af[s][ta] = *(const bf16x8*)(arow_base + (size_t)ta * 16 * D + t * 32);

        // sb groups ordered 2,1,0 so first MFMAs need only plane-0 A; plane-2 A used last
#pragma unroll
        for (int g = 0; g < 3; ++g) {
            const int sb = 2 - g;
            bf16x8 bfr[4];
#pragma unroll
            for (int tb = 0; tb < 4; ++tb)
                bfr[tb] = *(const bf16x8*)&Bs[buf][sb * 4096 + (wy * 4 + tb) * 512 + bswz];
#pragma unroll
            for (int sa = 0; sa <= 2 - sb; ++sa) {
#pragma unroll
                for (int ta = 0; ta < 4; ++ta)
#pragma unroll
                    for (int tb = 0; tb < 4; ++tb)
                        acc[ta][tb] = __builtin_amdgcn_mfma_f32_16x16x32_bf16(
                            af[sa][ta], bfr[tb], acc[ta][tb], 0, 0, 0);
            }
        }
    }

    // ---- epilogue: candidate collection (C/D layout: col=lane&15, row=(lane>>4)*4+reg) ----
    int ncol[4]; bool okn[4];
#pragma unroll
    for (int tb = 0; tb < 4; ++tb) {
        int n = col0 + wy * 64 + tb * 16 + mq;
        ncol[tb] = n;
        okn[tb] = (n < M) && (values[n] != -1);
    }
#pragma unroll
    for (int ta = 0; ta < 4; ++ta) {
        int rbase = row0 + wx * 64 + ta * 16 + qd * 4;
#pragma unroll
        for (int tb = 0; tb < 4; ++tb) {
            if (!okn[tb]) continue;
#pragma unroll
            for (int rg = 0; rg < 4; ++rg) {
                float s = acc[ta][tb][rg];
                if (s >= TAU) {
                    int r = rbase + rg;
                    int pos = atomicAdd(&cnt[r], 1);
                    if (pos < CAP) cand[(size_t)r * CAP + pos] =
                        make_int2(__float_as_int(s), ncol[tb]);
                }
            }
        }
    }
#undef STAGE
}

// ---------------- selection: fine-histogram filter + small exact rank ----------------
__device__ __forceinline__ int fbin(float s) {
    return (int)fminf((s - TAU) * FSCALE, (float)(FBINS - 1));
}
__device__ __forceinline__ int score_bin(float s) {
    float t = fminf(fmaxf((s + 1.0f) * 1024.0f, 0.0f), 2047.0f);
    return (int)t;
}

__global__ __launch_bounds__(256)
void select_kernel(const float* __restrict__ xn, const float* __restrict__ keys,
                   const float* __restrict__ kinv, const int* __restrict__ values,
                   const int* __restrict__ kptr, float* __restrict__ out,
                   const int2* __restrict__ cand, const int* __restrict__ cnt,
                   int M, int D, int C) {
    const int row = blockIdx.x;
    const int tid = threadIdx.x;
    const int K = *kptr;

    __shared__ float cs[SCAP];
    __shared__ int ci[SCAP];
    __shared__ int hist[NBINS];
    __shared__ float ss[SSCAP];
    __shared__ int si[SSCAP];
    __shared__ float xrow[512];
    __shared__ float accs[32];
    __shared__ int scnt, mcnt, tb;

    const int n0 = cnt[row];
    bool fast = (n0 >= K && n0 <= CAP);
    int m = 0;

    if (tid < 32) accs[tid] = 0.f;
    if (tid == 0) { scnt = 0; mcnt = 0; }

    if (fast) {
        for (int i = tid; i < FBINS; i += 256) hist[i] = 0;
        __syncthreads();
        for (int i = tid; i < n0; i += 256) {
            int2 p = cand[(size_t)row * CAP + i];
            float s = __int_as_float(p.x);
            cs[i] = s; ci[i] = p.y;
            atomicAdd(&hist[fbin(s)], 1);
        }
        __syncthreads();
        if (tid < 64) {
            const int lane = tid;
            int csum = 0;
#pragma unroll
            for (int j = 0; j < FBINS / 64; ++j) csum += hist[lane * (FBINS / 64) + j];
            int sfx = csum;
#pragma unroll
            for (int off = 1; off < 64; off <<= 1) {
                int o = __shfl_down(sfx, off);
                if (lane + off < 64) sfx += o;
            }
            unsigned long long mask = __ballot(sfx >= K);
            int L = 63 - __builtin_clzll(mask);
            int above = (L == 63) ? 0 : __shfl(sfx, L + 1);
            if (lane == L) {
                int c = above;
                int t = L * (FBINS / 64);
                for (int j = FBINS / 64 - 1; j >= 0; --j) {
                    c += hist[L * (FBINS / 64) + j];
                    if (c >= K) { t = L * (FBINS / 64) + j; break; }
                }
                tb = t;
            }
        }
        __syncthreads();
        const int T = tb;
        for (int i = tid; i < n0; i += 256) {
            if (fbin(cs[i]) >= T) {
                int p = atomicAdd(&mcnt, 1);
                if (p < SSCAP) { ss[p] = cs[i]; si[p] = ci[i]; }
            }
        }
        __syncthreads();
        m = mcnt;
        if (m > SSCAP) fast = false;
    }

    if (!fast) {
        for (int d = tid; d < D; d += 256) xrow[d] = xn[(size_t)row * D + d];
        for (int i = tid; i < NBINS; i += 256) hist[i] = 0;
        __syncthreads();
        for (int mm = tid; mm < M; mm += 256) {
            float s;
            if (values[mm] == -1) s = NEG_INF_V;
            else {
                const float4* kr = (const float4*)(keys + (size_t)mm * D);
                float sum = 0.f;
                for (int d4 = 0; d4 < D / 4; ++d4) {
                    float4 t = kr[d4];
                    const float4* xq = (const float4*)&xrow[d4 * 4];
                    sum += t.x * xq->x + t.y * xq->y + t.z * xq->z + t.w * xq->w;
                }
                s = sum * kinv[mm];
            }
            atomicAdd(&hist[score_bin(s)], 1);
        }
        __syncthreads();
        if (tid < 64) {
            const int lane = tid;
            int csum = 0;
#pragma unroll
            for (int j = 0; j < NBINS / 64; ++j) csum += hist[lane * (NBINS / 64) + j];
            int sfx = csum;
#pragma unroll
            for (int off = 1; off < 64; off <<= 1) {
                int o = __shfl_down(sfx, off);
                if (lane + off < 64) sfx += o;
            }
            unsigned long long mask = __ballot(sfx >= K);
            int L = 63 - __builtin_clzll(mask);
            int above = (L == 63) ? 0 : __shfl(sfx, L + 1);
            if (lane == L) {
                int c = above;
                int t = L * (NBINS / 64);
                for (int j = NBINS / 64 - 1; j >= 0; --j) {
                    c += hist[L * (NBINS / 64) + j];
                    if (c >= K) { t = L * (NBINS / 64) + j; break; }
                }
                tb = t;
            }
        }
        __syncthreads();
        const int T = tb;
        for (int mm = tid; mm < M; mm += 256) {
            float s;
            if (values[mm] == -1) s = NEG_INF_V;
            else {
                const float4* kr = (const float4*)(keys + (size_t)mm * D);
                float sum = 0.f;
                for (int d4 = 0; d4 < D / 4; ++d4) {
                    float4 t = kr[d4];
                    const float4* xq = (const float4*)&xrow[d4 * 4];
                    sum += t.x * xq->x + t.y * xq->y + t.z * xq->z + t.w * xq->w;
                }
                s = sum * kinv[mm];
            }
            if (score_bin(s) >= T) {
                int p = atomicAdd(&scnt, 1);
                if (p < SCAP) { cs[p] = s; ci[p] = mm; }
            }
        }
        __syncthreads();
        m = scnt < SCAP ? scnt : SCAP;
    }

    const float* rs = fast ? ss : cs;
    const int* ri = fast ? si : ci;
    for (int i = tid; i < m; i += 256) {
        float s = rs[i];
        int idx = ri[i];
        int rank = 0;
        for (int j = 0; j < m; ++j) {
            float sj = rs[j];
            rank += (sj > s) || (sj == s && ri[j] < idx);
        }
        if (rank < K) {
            int lbl = values[idx];
            if (lbl >= 0) atomicAdd(&accs[lbl], s);
        }
    }
    __syncthreads();
    if (tid < C) out[(size_t)row * C + tid] = accs[tid];
}

extern "C" void kernel_launch(void* const* d_in, const int* in_sizes, int n_in,
                              void* d_out, int out_size, void* d_ws, size_t ws_size,
                              hipStream_t stream) {
    const float* x = (const float*)d_in[0];
    const float* keys = (const float*)d_in[1];
    const int* values = (const int*)d_in[2];
    const int* kptr = (const int*)d_in[3];
    float* out = (float*)d_out;

    const int M = in_sizes[2];            // 60000
    const int D = in_sizes[1] / M;        // 512
    const int B = in_sizes[0] / D;        // 1024
    const int C = out_size / B;           // 10
    const int nk = D / 32;                // 16 k-chunks
    const int nct = (M + BN - 1) / BN;    // 469 col tiles
    const size_t xplane = (size_t)B * D;
    const size_t kplane = (size_t)nct * nk * 4096;

    char* wp = (char*)d_ws;
    float* xn = (float*)wp;                wp += (size_t)B * D * 4;
    float* kinv = (float*)wp;              wp += ((size_t)M * 4 + 255) / 256 * 256;
    int* cnt = (int*)wp;                   wp += (size_t)B * 4;
    int2* cand = (int2*)wp;                wp += (size_t)B * CAP * 8;
    unsigned short* Xs = (unsigned short*)wp;  wp += 3 * xplane * 2;
    unsigned short* K0 = (unsigned short*)wp;  wp += kplane * 2;
    unsigned short* K1 = (unsigned short*)wp;  wp += kplane * 2;
    unsigned short* K2 = (unsigned short*)wp;

    hipMemsetAsync(cnt, 0, (size_t)B * sizeof(int), stream);

    xnsplit_kernel<<<B, 64, 0, stream>>>(x, xn, Xs, xplane, D);
    kinv_kernel<<<(M + 3) / 4, 256, 0, stream>>>(keys, kinv, M, D);
    ksplit_kernel<<<nct * nk, 256, 0, stream>>>(keys, kinv, K0, K1, K2, M, D, nk);

    dim3 ggrid(B / BM, nct);
    gemm_kernel<<<ggrid, 256, 0, stream>>>(Xs, K0, values, cand, cnt,
                                           M, D, nk, xplane, kplane);

    select_kernel<<<B, 256, 0, stream>>>(xn, keys, kinv, values, kptr, out,
                                         cand, cnt, M, D, C);
}

// Round 7
// 907.197 us; speedup vs baseline: 34.3794x; 34.3794x over previous
//
#include <hip/hip_runtime.h>
#include <math.h>

#define BM 128
#define BN 128
#define EPSV 1e-12f
#define NEG_INF_V -1000000000.0f
#define NBINS 2048
#define FBINS 1024
#define FSCALE 5120.0f
#define SCAP 2048
#define CAP 2048
#define SSCAP 1024
#define TAU 0.10f

typedef __attribute__((ext_vector_type(8))) short bf16x8;
typedef __attribute__((ext_vector_type(4))) float f32x4;

__device__ __forceinline__ unsigned short f2bf(float f) {
    unsigned int u = __float_as_uint(f);
    unsigned int r = (u + 0x7fffu + ((u >> 16) & 1u)) >> 16;
    return (unsigned short)r;
}
__device__ __forceinline__ float bf2f(unsigned short h) {
    return __uint_as_float(((unsigned int)h) << 16);
}
__device__ __forceinline__ void split3(float v, unsigned short& h0,
                                       unsigned short& h1, unsigned short& h2) {
    h0 = f2bf(v); float r = v - bf2f(h0);
    h1 = f2bf(r); r -= bf2f(h1);
    h2 = f2bf(r);
}
__device__ __forceinline__ void gload_lds16(const unsigned short* g, const unsigned short* l) {
    __builtin_amdgcn_global_load_lds((const __attribute__((address_space(1))) void*)g,
                                     (__attribute__((address_space(3))) void*)l, 16, 0, 0);
}

// ------- fused: normalize x rows + split into 3 bf16 planes (one wave per row) -------
__global__ void xnsplit_kernel(const float* __restrict__ x, float* __restrict__ xn,
                               unsigned short* __restrict__ Xs, size_t xplane, int D) {
    int row = blockIdx.x;
    int lane = threadIdx.x;
    const float4* xr = (const float4*)(x + (size_t)row * D);
    float4* xo = (float4*)(xn + (size_t)row * D);
    int per = (D / 4) / 64;          // D=512 -> 2
    float ss = 0.f;
    float4 v[2];
    for (int i = 0; i < per; ++i) {
        float4 t = xr[lane * per + i];
        v[i] = t;
        ss += t.x * t.x + t.y * t.y + t.z * t.z + t.w * t.w;
    }
    for (int off = 32; off >= 1; off >>= 1) ss += __shfl_xor(ss, off);
    float denom = fmaxf(sqrtf(ss), EPSV);
    float vals[8];
    for (int i = 0; i < per; ++i) {
        float4 t = v[i];
        t.x /= denom; t.y /= denom; t.z /= denom; t.w /= denom;
        xo[lane * per + i] = t;
        vals[i * 4 + 0] = t.x; vals[i * 4 + 1] = t.y;
        vals[i * 4 + 2] = t.z; vals[i * 4 + 3] = t.w;
    }
    unsigned short h0[8], h1[8], h2[8];
#pragma unroll
    for (int i = 0; i < 8; ++i) split3(vals[i], h0[i], h1[i], h2[i]);
    size_t off0 = (size_t)row * D + lane * 8;
    *(bf16x8*)(Xs + off0)              = *(bf16x8*)h0;
    *(bf16x8*)(Xs + xplane + off0)     = *(bf16x8*)h1;
    *(bf16x8*)(Xs + 2 * xplane + off0) = *(bf16x8*)h2;
}

// ---------------- key inverse norms (one wave per key row) ----------------
__global__ void kinv_kernel(const float* __restrict__ keys, float* __restrict__ kinv,
                            int M, int D) {
    int wave = threadIdx.x >> 6;
    int lane = threadIdx.x & 63;
    int row = blockIdx.x * 4 + wave;
    if (row >= M) return;
    const float4* kr = (const float4*)(keys + (size_t)row * D);
    int per = (D / 4) / 64;
    float ss = 0.f;
    for (int i = 0; i < per; ++i) {
        float4 t = kr[lane * per + i];
        ss += t.x * t.x + t.y * t.y + t.z * t.z + t.w * t.w;
    }
    for (int off = 32; off >= 1; off >>= 1) ss += __shfl_xor(ss, off);
    if (lane == 0) kinv[row] = 1.0f / fmaxf(sqrtf(ss), EPSV);
}

// ------- split keys*kinv into 3 bf16 planes, packed per (col-tile, k-chunk) in
// ------- fragment order with XOR bank swizzle ----------
__global__ __launch_bounds__(256)
void ksplit_kernel(const float* __restrict__ keys, const float* __restrict__ kinv,
                   unsigned short* __restrict__ K0, unsigned short* __restrict__ K1,
                   unsigned short* __restrict__ K2, int M, int D, int nk) {
    const int ct = blockIdx.x / nk;
    const int t  = blockIdx.x % nk;
    const size_t blk = (size_t)blockIdx.x * 4096;   // shorts
#pragma unroll
    for (int half = 0; half < 2; ++half) {
        int sig = half * 256 + threadIdx.x;         // slot 0..511
        int tau = sig >> 6;
        int mp  = (sig >> 2) & 15;
        int qp  = sig & 3;
        int row = ct * 128 + tau * 16 + mp;
        int qs  = qp ^ (mp & 3);
        unsigned short h0[8], h1[8], h2[8];
        if (row < M) {
            float inv = kinv[row];
            const float* src = keys + (size_t)row * D + t * 32 + qs * 8;
#pragma unroll
            for (int i = 0; i < 8; ++i) split3(src[i] * inv, h0[i], h1[i], h2[i]);
        } else {
#pragma unroll
            for (int i = 0; i < 8; ++i) { h0[i] = 0; h1[i] = 0; h2[i] = 0; }
        }
        size_t off = blk + (size_t)sig * 8;
        *(bf16x8*)(K0 + off) = *(bf16x8*)h0;
        *(bf16x8*)(K1 + off) = *(bf16x8*)h1;
        *(bf16x8*)(K2 + off) = *(bf16x8*)h2;
    }
}

// ---------------- MFMA GEMM: 128x128 block, 4 waves 2x2, 6 split-products ----------------
// 3 blocks/CU (LDS 48KB). Product order sb=2,1,0 with plane-2 A loaded last, used last.
__global__ __launch_bounds__(256, 3)
void gemm_kernel(const unsigned short* __restrict__ Xs,   // 3 planes, stride xplane
                 const unsigned short* __restrict__ Kp,   // 3 packed planes, stride kplane
                 const int* __restrict__ values,
                 int2* __restrict__ cand, int* __restrict__ cnt,
                 int M, int D, int nk, size_t xplane, size_t kplane) {
    __shared__ unsigned short Bs[2][3 * 4096];   // 2 x 24 KB

    const int tid  = threadIdx.x;
    const int lane = tid & 63;
    const int w    = tid >> 6;
    const int wx   = w >> 1, wy = w & 1;
    const int rt   = blockIdx.x;
    const int ct   = blockIdx.y;
    const int row0 = rt * BM, col0 = ct * BN;
    const int mq   = lane & 15;
    const int qd   = lane >> 4;
    const int bswz = mq * 32 + ((qd ^ (mq & 3)) << 3);

    f32x4 acc[4][4];
#pragma unroll
    for (int i = 0; i < 4; ++i)
#pragma unroll
        for (int j = 0; j < 4; ++j) acc[i][j] = (f32x4){0.f, 0.f, 0.f, 0.f};

#define STAGE(t_, buf_)                                                          \
    {                                                                            \
        const size_t blk_ = ((size_t)ct * nk + (t_)) * 4096;                     \
        _Pragma("unroll")                                                        \
        for (int i_ = 0; i_ < 6; ++i_) {                                         \
            int s_ = w + i_ * 4;                                                 \
            int sp_ = s_ >> 3, pt_ = s_ & 7;                                     \
            gload_lds16(Kp + (size_t)sp_ * kplane + blk_ + pt_ * 512 + lane * 8, \
                        &Bs[buf_][sp_ * 4096 + pt_ * 512]);                      \
        }                                                                        \
    }

    STAGE(0, 0);

    const unsigned short* arow_base = Xs + (size_t)(row0 + wx * 64 + mq) * D + qd * 8;

    for (int t = 0; t < nk; ++t) {
        const int buf = t & 1;
        __syncthreads();                          // Bs[buf] staged; drains in-flight loads

        if (t + 1 < nk) STAGE(t + 1, buf ^ 1);    // longest-latency first: full chunk of slack

        // A fragments, issued in use order (plane 0 first, plane 2 last-used)
        bf16x8 af[3][4];
#pragma unroll
        for (int s = 0; s < 3; ++s)
#pragma unroll
            for (int ta = 0; ta < 4; ++ta)
                af[s][ta] = *(const bf16x8*)(arow_base + (size_t)s * xplane +   // <-- plane offset (r6 bug fixed)
                                             (size_t)ta * 16 * D + t * 32);

        // sb groups ordered 2,1,0 so first MFMAs need only plane-0 A; plane-2 A used last
#pragma unroll
        for (int g = 0; g < 3; ++g) {
            const int sb = 2 - g;
            bf16x8 bfr[4];
#pragma unroll
            for (int tb = 0; tb < 4; ++tb)
                bfr[tb] = *(const bf16x8*)&Bs[buf][sb * 4096 + (wy * 4 + tb) * 512 + bswz];
#pragma unroll
            for (int sa = 0; sa <= 2 - sb; ++sa) {
#pragma unroll
                for (int ta = 0; ta < 4; ++ta)
#pragma unroll
                    for (int tb = 0; tb < 4; ++tb)
                        acc[ta][tb] = __builtin_amdgcn_mfma_f32_16x16x32_bf16(
                            af[sa][ta], bfr[tb], acc[ta][tb], 0, 0, 0);
            }
        }
    }

    // ---- epilogue: candidate collection (C/D layout: col=lane&15, row=(lane>>4)*4+reg) ----
    int ncol[4]; bool okn[4];
#pragma unroll
    for (int tb = 0; tb < 4; ++tb) {
        int n = col0 + wy * 64 + tb * 16 + mq;
        ncol[tb] = n;
        okn[tb] = (n < M) && (values[n] != -1);
    }
#pragma unroll
    for (int ta = 0; ta < 4; ++ta) {
        int rbase = row0 + wx * 64 + ta * 16 + qd * 4;
#pragma unroll
        for (int tb = 0; tb < 4; ++tb) {
            if (!okn[tb]) continue;
#pragma unroll
            for (int rg = 0; rg < 4; ++rg) {
                float s = acc[ta][tb][rg];
                if (s >= TAU) {
                    int r = rbase + rg;
                    int pos = atomicAdd(&cnt[r], 1);
                    if (pos < CAP) cand[(size_t)r * CAP + pos] =
                        make_int2(__float_as_int(s), ncol[tb]);
                }
            }
        }
    }
#undef STAGE
}

// ---------------- selection: fine-histogram filter + small exact rank ----------------
__device__ __forceinline__ int fbin(float s) {
    return (int)fminf((s - TAU) * FSCALE, (float)(FBINS - 1));
}
__device__ __forceinline__ int score_bin(float s) {
    float t = fminf(fmaxf((s + 1.0f) * 1024.0f, 0.0f), 2047.0f);
    return (int)t;
}

__global__ __launch_bounds__(256)
void select_kernel(const float* __restrict__ xn, const float* __restrict__ keys,
                   const float* __restrict__ kinv, const int* __restrict__ values,
                   const int* __restrict__ kptr, float* __restrict__ out,
                   const int2* __restrict__ cand, const int* __restrict__ cnt,
                   int M, int D, int C) {
    const int row = blockIdx.x;
    const int tid = threadIdx.x;
    const int K = *kptr;

    __shared__ float cs[SCAP];
    __shared__ int ci[SCAP];
    __shared__ int hist[NBINS];
    __shared__ float ss[SSCAP];
    __shared__ int si[SSCAP];
    __shared__ float xrow[512];
    __shared__ float accs[32];
    __shared__ int scnt, mcnt, tb;

    const int n0 = cnt[row];
    bool fast = (n0 >= K && n0 <= CAP);
    int m = 0;

    if (tid < 32) accs[tid] = 0.f;
    if (tid == 0) { scnt = 0; mcnt = 0; }

    if (fast) {
        for (int i = tid; i < FBINS; i += 256) hist[i] = 0;
        __syncthreads();
        for (int i = tid; i < n0; i += 256) {
            int2 p = cand[(size_t)row * CAP + i];
            float s = __int_as_float(p.x);
            cs[i] = s; ci[i] = p.y;
            atomicAdd(&hist[fbin(s)], 1);
        }
        __syncthreads();
        if (tid < 64) {
            const int lane = tid;
            int csum = 0;
#pragma unroll
            for (int j = 0; j < FBINS / 64; ++j) csum += hist[lane * (FBINS / 64) + j];
            int sfx = csum;
#pragma unroll
            for (int off = 1; off < 64; off <<= 1) {
                int o = __shfl_down(sfx, off);
                if (lane + off < 64) sfx += o;
            }
            unsigned long long mask = __ballot(sfx >= K);
            int L = 63 - __builtin_clzll(mask);
            int above = (L == 63) ? 0 : __shfl(sfx, L + 1);
            if (lane == L) {
                int c = above;
                int t = L * (FBINS / 64);
                for (int j = FBINS / 64 - 1; j >= 0; --j) {
                    c += hist[L * (FBINS / 64) + j];
                    if (c >= K) { t = L * (FBINS / 64) + j; break; }
                }
                tb = t;
            }
        }
        __syncthreads();
        const int T = tb;
        for (int i = tid; i < n0; i += 256) {
            if (fbin(cs[i]) >= T) {
                int p = atomicAdd(&mcnt, 1);
                if (p < SSCAP) { ss[p] = cs[i]; si[p] = ci[i]; }
            }
        }
        __syncthreads();
        m = mcnt;
        if (m > SSCAP) fast = false;
    }

    if (!fast) {
        for (int d = tid; d < D; d += 256) xrow[d] = xn[(size_t)row * D + d];
        for (int i = tid; i < NBINS; i += 256) hist[i] = 0;
        __syncthreads();
        for (int mm = tid; mm < M; mm += 256) {
            float s;
            if (values[mm] == -1) s = NEG_INF_V;
            else {
                const float4* kr = (const float4*)(keys + (size_t)mm * D);
                float sum = 0.f;
                for (int d4 = 0; d4 < D / 4; ++d4) {
                    float4 t = kr[d4];
                    const float4* xq = (const float4*)&xrow[d4 * 4];
                    sum += t.x * xq->x + t.y * xq->y + t.z * xq->z + t.w * xq->w;
                }
                s = sum * kinv[mm];
            }
            atomicAdd(&hist[score_bin(s)], 1);
        }
        __syncthreads();
        if (tid < 64) {
            const int lane = tid;
            int csum = 0;
#pragma unroll
            for (int j = 0; j < NBINS / 64; ++j) csum += hist[lane * (NBINS / 64) + j];
            int sfx = csum;
#pragma unroll
            for (int off = 1; off < 64; off <<= 1) {
                int o = __shfl_down(sfx, off);
                if (lane + off < 64) sfx += o;
            }
            unsigned long long mask = __ballot(sfx >= K);
            int L = 63 - __builtin_clzll(mask);
            int above = (L == 63) ? 0 : __shfl(sfx, L + 1);
            if (lane == L) {
                int c = above;
                int t = L * (NBINS / 64);
                for (int j = NBINS / 64 - 1; j >= 0; --j) {
                    c += hist[L * (NBINS / 64) + j];
                    if (c >= K) { t = L * (NBINS / 64) + j; break; }
                }
                tb = t;
            }
        }
        __syncthreads();
        const int T = tb;
        for (int mm = tid; mm < M; mm += 256) {
            float s;
            if (values[mm] == -1) s = NEG_INF_V;
            else {
                const float4* kr = (const float4*)(keys + (size_t)mm * D);
                float sum = 0.f;
                for (int d4 = 0; d4 < D / 4; ++d4) {
                    float4 t = kr[d4];
                    const float4* xq = (const float4*)&xrow[d4 * 4];
                    sum += t.x * xq->x + t.y * xq->y + t.z * xq->z + t.w * xq->w;
                }
                s = sum * kinv[mm];
            }
            if (score_bin(s) >= T) {
                int p = atomicAdd(&scnt, 1);
                if (p < SCAP) { cs[p] = s; ci[p] = mm; }
            }
        }
        __syncthreads();
        m = scnt < SCAP ? scnt : SCAP;
    }

    const float* rs = fast ? ss : cs;
    const int* ri = fast ? si : ci;
    for (int i = tid; i < m; i += 256) {
        float s = rs[i];
        int idx = ri[i];
        int rank = 0;
        for (int j = 0; j < m; ++j) {
            float sj = rs[j];
            rank += (sj > s) || (sj == s && ri[j] < idx);
        }
        if (rank < K) {
            int lbl = values[idx];
            if (lbl >= 0) atomicAdd(&accs[lbl], s);
        }
    }
    __syncthreads();
    if (tid < C) out[(size_t)row * C + tid] = accs[tid];
}

extern "C" void kernel_launch(void* const* d_in, const int* in_sizes, int n_in,
                              void* d_out, int out_size, void* d_ws, size_t ws_size,
                              hipStream_t stream) {
    const float* x = (const float*)d_in[0];
    const float* keys = (const float*)d_in[1];
    const int* values = (const int*)d_in[2];
    const int* kptr = (const int*)d_in[3];
    float* out = (float*)d_out;

    const int M = in_sizes[2];            // 60000
    const int D = in_sizes[1] / M;        // 512
    const int B = in_sizes[0] / D;        // 1024
    const int C = out_size / B;           // 10
    const int nk = D / 32;                // 16 k-chunks
    const int nct = (M + BN - 1) / BN;    // 469 col tiles
    const size_t xplane = (size_t)B * D;
    const size_t kplane = (size_t)nct * nk * 4096;

    char* wp = (char*)d_ws;
    float* xn = (float*)wp;                wp += (size_t)B * D * 4;
    float* kinv = (float*)wp;              wp += ((size_t)M * 4 + 255) / 256 * 256;
    int* cnt = (int*)wp;                   wp += (size_t)B * 4;
    int2* cand = (int2*)wp;                wp += (size_t)B * CAP * 8;
    unsigned short* Xs = (unsigned short*)wp;  wp += 3 * xplane * 2;
    unsigned short* K0 = (unsigned short*)wp;  wp += kplane * 2;
    unsigned short* K1 = (unsigned short*)wp;  wp += kplane * 2;
    unsigned short* K2 = (unsigned short*)wp;

    hipMemsetAsync(cnt, 0, (size_t)B * sizeof(int), stream);

    xnsplit_kernel<<<B, 64, 0, stream>>>(x, xn, Xs, xplane, D);
    kinv_kernel<<<(M + 3) / 4, 256, 0, stream>>>(keys, kinv, M, D);
    ksplit_kernel<<<nct * nk, 256, 0, stream>>>(keys, kinv, K0, K1, K2, M, D, nk);

    dim3 ggrid(B / BM, nct);
    gemm_kernel<<<ggrid, 256, 0, stream>>>(Xs, K0, values, cand, cnt,
                                           M, D, nk, xplane, kplane);

    select_kernel<<<B, 256, 0, stream>>>(xn, keys, kinv, values, kptr, out,
                                         cand, cnt, M, D, C);
}

// Round 8
// 733.694 us; speedup vs baseline: 42.5095x; 1.2365x over previous
//
#include <hip/hip_runtime.h>
#include <math.h>

#define BM 128
#define BN 128
#define EPSV 1e-12f
#define NEG_INF_V -1000000000.0f
#define NBINS 2048
#define FBINS 1024
#define FSCALE 5120.0f
#define SCAP 2048
#define CAP 2048
#define SSCAP 1024
#define TAU 0.10f

typedef __attribute__((ext_vector_type(8))) short bf16x8;
typedef __attribute__((ext_vector_type(4))) float f32x4;

__device__ __forceinline__ unsigned short f2bf(float f) {
    unsigned int u = __float_as_uint(f);
    unsigned int r = (u + 0x7fffu + ((u >> 16) & 1u)) >> 16;
    return (unsigned short)r;
}
__device__ __forceinline__ float bf2f(unsigned short h) {
    return __uint_as_float(((unsigned int)h) << 16);
}
__device__ __forceinline__ void split3(float v, unsigned short& h0,
                                       unsigned short& h1, unsigned short& h2) {
    h0 = f2bf(v); float r = v - bf2f(h0);
    h1 = f2bf(r); r -= bf2f(h1);
    h2 = f2bf(r);
}
__device__ __forceinline__ void gload_lds16(const unsigned short* g, const unsigned short* l) {
    __builtin_amdgcn_global_load_lds((const __attribute__((address_space(1))) void*)g,
                                     (__attribute__((address_space(3))) void*)l, 16, 0, 0);
}

// ------- fused: normalize x rows + split into 3 bf16 planes (one wave per row) -------
__global__ void xnsplit_kernel(const float* __restrict__ x, float* __restrict__ xn,
                               unsigned short* __restrict__ Xs, size_t xplane, int D) {
    int row = blockIdx.x;
    int lane = threadIdx.x;
    const float4* xr = (const float4*)(x + (size_t)row * D);
    float4* xo = (float4*)(xn + (size_t)row * D);
    int per = (D / 4) / 64;          // D=512 -> 2
    float ss = 0.f;
    float4 v[2];
    for (int i = 0; i < per; ++i) {
        float4 t = xr[lane * per + i];
        v[i] = t;
        ss += t.x * t.x + t.y * t.y + t.z * t.z + t.w * t.w;
    }
    for (int off = 32; off >= 1; off >>= 1) ss += __shfl_xor(ss, off);
    float denom = fmaxf(sqrtf(ss), EPSV);
    float vals[8];
    for (int i = 0; i < per; ++i) {
        float4 t = v[i];
        t.x /= denom; t.y /= denom; t.z /= denom; t.w /= denom;
        xo[lane * per + i] = t;
        vals[i * 4 + 0] = t.x; vals[i * 4 + 1] = t.y;
        vals[i * 4 + 2] = t.z; vals[i * 4 + 3] = t.w;
    }
    unsigned short h0[8], h1[8], h2[8];
#pragma unroll
    for (int i = 0; i < 8; ++i) split3(vals[i], h0[i], h1[i], h2[i]);
    size_t off0 = (size_t)row * D + lane * 8;
    *(bf16x8*)(Xs + off0)              = *(bf16x8*)h0;
    *(bf16x8*)(Xs + xplane + off0)     = *(bf16x8*)h1;
    *(bf16x8*)(Xs + 2 * xplane + off0) = *(bf16x8*)h2;
}

// ---------------- key inverse norms (one wave per key row) ----------------
__global__ void kinv_kernel(const float* __restrict__ keys, float* __restrict__ kinv,
                            int M, int D) {
    int wave = threadIdx.x >> 6;
    int lane = threadIdx.x & 63;
    int row = blockIdx.x * 4 + wave;
    if (row >= M) return;
    const float4* kr = (const float4*)(keys + (size_t)row * D);
    int per = (D / 4) / 64;
    float ss = 0.f;
    for (int i = 0; i < per; ++i) {
        float4 t = kr[lane * per + i];
        ss += t.x * t.x + t.y * t.y + t.z * t.z + t.w * t.w;
    }
    for (int off = 32; off >= 1; off >>= 1) ss += __shfl_xor(ss, off);
    if (lane == 0) kinv[row] = 1.0f / fmaxf(sqrtf(ss), EPSV);
}

// ------- split keys*kinv into 3 bf16 planes, packed per (col-tile, k-chunk) in
// ------- fragment order with XOR bank swizzle ----------
__global__ __launch_bounds__(256)
void ksplit_kernel(const float* __restrict__ keys, const float* __restrict__ kinv,
                   unsigned short* __restrict__ K0, unsigned short* __restrict__ K1,
                   unsigned short* __restrict__ K2, int M, int D, int nk) {
    const int ct = blockIdx.x / nk;
    const int t  = blockIdx.x % nk;
    const size_t blk = (size_t)blockIdx.x * 4096;   // shorts
#pragma unroll
    for (int half = 0; half < 2; ++half) {
        int sig = half * 256 + threadIdx.x;         // slot 0..511
        int tau = sig >> 6;
        int mp  = (sig >> 2) & 15;
        int qp  = sig & 3;
        int row = ct * 128 + tau * 16 + mp;
        int qs  = qp ^ (mp & 3);
        unsigned short h0[8], h1[8], h2[8];
        if (row < M) {
            float inv = kinv[row];
            const float* src = keys + (size_t)row * D + t * 32 + qs * 8;
#pragma unroll
            for (int i = 0; i < 8; ++i) split3(src[i] * inv, h0[i], h1[i], h2[i]);
        } else {
#pragma unroll
            for (int i = 0; i < 8; ++i) { h0[i] = 0; h1[i] = 0; h2[i] = 0; }
        }
        size_t off = blk + (size_t)sig * 8;
        *(bf16x8*)(K0 + off) = *(bf16x8*)h0;
        *(bf16x8*)(K1 + off) = *(bf16x8*)h1;
        *(bf16x8*)(K2 + off) = *(bf16x8*)h2;
    }
}

// ---------------- MFMA GEMM: 128x128 block, 4 waves 2x2, 6 split-products ----------------
// r5 loop-body order (A-loads BEFORE staging: vmcnt in-order => A-wait doesn't drain
// staging queue). XCD swizzle: all 8 rt-blocks of a ct share l%8 => same XCD L2.
__global__ __launch_bounds__(256, 3)
void gemm_kernel(const unsigned short* __restrict__ Xs,   // 3 planes, stride xplane
                 const unsigned short* __restrict__ Kp,   // 3 packed planes, stride kplane
                 const int* __restrict__ values,
                 int2* __restrict__ cand, int* __restrict__ cnt,
                 int M, int D, int nk, int nct, size_t xplane, size_t kplane) {
    const int l  = blockIdx.x;
    const int ct = (l & 7) + ((l >> 6) << 3);
    const int rt = (l >> 3) & 7;
    if (ct >= nct) return;

    __shared__ unsigned short Bs[2][3 * 4096];   // 2 x 24 KB

    const int tid  = threadIdx.x;
    const int lane = tid & 63;
    const int w    = tid >> 6;
    const int wx   = w >> 1, wy = w & 1;
    const int row0 = rt * BM, col0 = ct * BN;
    const int mq   = lane & 15;
    const int qd   = lane >> 4;
    const int bswz = mq * 32 + ((qd ^ (mq & 3)) << 3);

    f32x4 acc[4][4];
#pragma unroll
    for (int i = 0; i < 4; ++i)
#pragma unroll
        for (int j = 0; j < 4; ++j) acc[i][j] = (f32x4){0.f, 0.f, 0.f, 0.f};

#define STAGE(t_, buf_)                                                          \
    {                                                                            \
        const size_t blk_ = ((size_t)ct * nk + (t_)) * 4096;                     \
        _Pragma("unroll")                                                        \
        for (int i_ = 0; i_ < 6; ++i_) {                                         \
            int s_ = w + i_ * 4;                                                 \
            int sp_ = s_ >> 3, pt_ = s_ & 7;                                     \
            gload_lds16(Kp + (size_t)sp_ * kplane + blk_ + pt_ * 512 + lane * 8, \
                        &Bs[buf_][sp_ * 4096 + pt_ * 512]);                      \
        }                                                                        \
    }

    STAGE(0, 0);

    const unsigned short* arow_base = Xs + (size_t)(row0 + wx * 64 + mq) * D + qd * 8;

    for (int t = 0; t < nk; ++t) {
        const int buf = t & 1;
        __syncthreads();                          // Bs[buf] staged; drains in-flight loads

        // A fragments FIRST (ahead of staging in the vmcnt queue)
        bf16x8 af[3][4];
#pragma unroll
        for (int s = 0; s < 3; ++s)
#pragma unroll
            for (int ta = 0; ta < 4; ++ta)
                af[s][ta] = *(const bf16x8*)(arow_base + (size_t)s * xplane +
                                             (size_t)ta * 16 * D + t * 32);

        if (t + 1 < nk) STAGE(t + 1, buf ^ 1);    // prefetch behind A in the queue

#pragma unroll
        for (int sb = 0; sb < 3; ++sb) {
            bf16x8 bfr[4];
#pragma unroll
            for (int tb = 0; tb < 4; ++tb)
                bfr[tb] = *(const bf16x8*)&Bs[buf][sb * 4096 + (wy * 4 + tb) * 512 + bswz];
#pragma unroll
            for (int sa = 0; sa <= 2 - sb; ++sa) {
#pragma unroll
                for (int ta = 0; ta < 4; ++ta)
#pragma unroll
                    for (int tb = 0; tb < 4; ++tb)
                        acc[ta][tb] = __builtin_amdgcn_mfma_f32_16x16x32_bf16(
                            af[sa][ta], bfr[tb], acc[ta][tb], 0, 0, 0);
            }
        }
    }

    // ---- epilogue: candidate collection (C/D layout: col=lane&15, row=(lane>>4)*4+reg) ----
    int ncol[4]; bool okn[4];
#pragma unroll
    for (int tb = 0; tb < 4; ++tb) {
        int n = col0 + wy * 64 + tb * 16 + mq;
        ncol[tb] = n;
        okn[tb] = (n < M) && (values[n] != -1);
    }
#pragma unroll
    for (int ta = 0; ta < 4; ++ta) {
        int rbase = row0 + wx * 64 + ta * 16 + qd * 4;
#pragma unroll
        for (int tb = 0; tb < 4; ++tb) {
            if (!okn[tb]) continue;
#pragma unroll
            for (int rg = 0; rg < 4; ++rg) {
                float s = acc[ta][tb][rg];
                if (s >= TAU) {
                    int r = rbase + rg;
                    int pos = atomicAdd(&cnt[r], 1);
                    if (pos < CAP) cand[(size_t)r * CAP + pos] =
                        make_int2(__float_as_int(s), ncol[tb]);
                }
            }
        }
    }
#undef STAGE
}

// ---------------- selection: fine-histogram filter + small exact rank ----------------
__device__ __forceinline__ int fbin(float s) {
    return (int)fminf((s - TAU) * FSCALE, (float)(FBINS - 1));
}
__device__ __forceinline__ int score_bin(float s) {
    float t = fminf(fmaxf((s + 1.0f) * 1024.0f, 0.0f), 2047.0f);
    return (int)t;
}

__global__ __launch_bounds__(256)
void select_kernel(const float* __restrict__ xn, const float* __restrict__ keys,
                   const float* __restrict__ kinv, const int* __restrict__ values,
                   const int* __restrict__ kptr, float* __restrict__ out,
                   const int2* __restrict__ cand, const int* __restrict__ cnt,
                   int M, int D, int C) {
    const int row = blockIdx.x;
    const int tid = threadIdx.x;
    const int K = *kptr;

    __shared__ float cs[SCAP];
    __shared__ int ci[SCAP];
    __shared__ int hist[NBINS];
    __shared__ float ss[SSCAP];
    __shared__ int si[SSCAP];
    __shared__ float xrow[512];
    __shared__ float accs[32];
    __shared__ int scnt, mcnt, tb;

    const int n0 = cnt[row];
    bool fast = (n0 >= K && n0 <= CAP);
    int m = 0;

    if (tid < 32) accs[tid] = 0.f;
    if (tid == 0) { scnt = 0; mcnt = 0; }

    if (fast) {
        for (int i = tid; i < FBINS; i += 256) hist[i] = 0;
        __syncthreads();
        for (int i = tid; i < n0; i += 256) {
            int2 p = cand[(size_t)row * CAP + i];
            float s = __int_as_float(p.x);
            cs[i] = s; ci[i] = p.y;
            atomicAdd(&hist[fbin(s)], 1);
        }
        __syncthreads();
        if (tid < 64) {
            const int lane = tid;
            int csum = 0;
#pragma unroll
            for (int j = 0; j < FBINS / 64; ++j) csum += hist[lane * (FBINS / 64) + j];
            int sfx = csum;
#pragma unroll
            for (int off = 1; off < 64; off <<= 1) {
                int o = __shfl_down(sfx, off);
                if (lane + off < 64) sfx += o;
            }
            unsigned long long mask = __ballot(sfx >= K);
            int L = 63 - __builtin_clzll(mask);
            int above = (L == 63) ? 0 : __shfl(sfx, L + 1);
            if (lane == L) {
                int c = above;
                int t = L * (FBINS / 64);
                for (int j = FBINS / 64 - 1; j >= 0; --j) {
                    c += hist[L * (FBINS / 64) + j];
                    if (c >= K) { t = L * (FBINS / 64) + j; break; }
                }
                tb = t;
            }
        }
        __syncthreads();
        const int T = tb;
        for (int i = tid; i < n0; i += 256) {
            if (fbin(cs[i]) >= T) {
                int p = atomicAdd(&mcnt, 1);
                if (p < SSCAP) { ss[p] = cs[i]; si[p] = ci[i]; }
            }
        }
        __syncthreads();
        m = mcnt;
        if (m > SSCAP) fast = false;
    }

    if (!fast) {
        for (int d = tid; d < D; d += 256) xrow[d] = xn[(size_t)row * D + d];
        for (int i = tid; i < NBINS; i += 256) hist[i] = 0;
        __syncthreads();
        for (int mm = tid; mm < M; mm += 256) {
            float s;
            if (values[mm] == -1) s = NEG_INF_V;
            else {
                const float4* kr = (const float4*)(keys + (size_t)mm * D);
                float sum = 0.f;
                for (int d4 = 0; d4 < D / 4; ++d4) {
                    float4 t = kr[d4];
                    const float4* xq = (const float4*)&xrow[d4 * 4];
                    sum += t.x * xq->x + t.y * xq->y + t.z * xq->z + t.w * xq->w;
                }
                s = sum * kinv[mm];
            }
            atomicAdd(&hist[score_bin(s)], 1);
        }
        __syncthreads();
        if (tid < 64) {
            const int lane = tid;
            int csum = 0;
#pragma unroll
            for (int j = 0; j < NBINS / 64; ++j) csum += hist[lane * (NBINS / 64) + j];
            int sfx = csum;
#pragma unroll
            for (int off = 1; off < 64; off <<= 1) {
                int o = __shfl_down(sfx, off);
                if (lane + off < 64) sfx += o;
            }
            unsigned long long mask = __ballot(sfx >= K);
            int L = 63 - __builtin_clzll(mask);
            int above = (L == 63) ? 0 : __shfl(sfx, L + 1);
            if (lane == L) {
                int c = above;
                int t = L * (NBINS / 64);
                for (int j = NBINS / 64 - 1; j >= 0; --j) {
                    c += hist[L * (NBINS / 64) + j];
                    if (c >= K) { t = L * (NBINS / 64) + j; break; }
                }
                tb = t;
            }
        }
        __syncthreads();
        const int T = tb;
        for (int mm = tid; mm < M; mm += 256) {
            float s;
            if (values[mm] == -1) s = NEG_INF_V;
            else {
                const float4* kr = (const float4*)(keys + (size_t)mm * D);
                float sum = 0.f;
                for (int d4 = 0; d4 < D / 4; ++d4) {
                    float4 t = kr[d4];
                    const float4* xq = (const float4*)&xrow[d4 * 4];
                    sum += t.x * xq->x + t.y * xq->y + t.z * xq->z + t.w * xq->w;
                }
                s = sum * kinv[mm];
            }
            if (score_bin(s) >= T) {
                int p = atomicAdd(&scnt, 1);
                if (p < SCAP) { cs[p] = s; ci[p] = mm; }
            }
        }
        __syncthreads();
        m = scnt < SCAP ? scnt : SCAP;
    }

    const float* rs = fast ? ss : cs;
    const int* ri = fast ? si : ci;
    for (int i = tid; i < m; i += 256) {
        float s = rs[i];
        int idx = ri[i];
        int rank = 0;
        for (int j = 0; j < m; ++j) {
            float sj = rs[j];
            rank += (sj > s) || (sj == s && ri[j] < idx);
        }
        if (rank < K) {
            int lbl = values[idx];
            if (lbl >= 0) atomicAdd(&accs[lbl], s);
        }
    }
    __syncthreads();
    if (tid < C) out[(size_t)row * C + tid] = accs[tid];
}

extern "C" void kernel_launch(void* const* d_in, const int* in_sizes, int n_in,
                              void* d_out, int out_size, void* d_ws, size_t ws_size,
                              hipStream_t stream) {
    const float* x = (const float*)d_in[0];
    const float* keys = (const float*)d_in[1];
    const int* values = (const int*)d_in[2];
    const int* kptr = (const int*)d_in[3];
    float* out = (float*)d_out;

    const int M = in_sizes[2];            // 60000
    const int D = in_sizes[1] / M;        // 512
    const int B = in_sizes[0] / D;        // 1024
    const int C = out_size / B;           // 10
    const int nk = D / 32;                // 16 k-chunks
    const int nct = (M + BN - 1) / BN;    // 469 col tiles
    const size_t xplane = (size_t)B * D;
    const size_t kplane = (size_t)nct * nk * 4096;

    char* wp = (char*)d_ws;
    float* xn = (float*)wp;                wp += (size_t)B * D * 4;
    float* kinv = (float*)wp;              wp += ((size_t)M * 4 + 255) / 256 * 256;
    int* cnt = (int*)wp;                   wp += (size_t)B * 4;
    int2* cand = (int2*)wp;                wp += (size_t)B * CAP * 8;
    unsigned short* Xs = (unsigned short*)wp;  wp += 3 * xplane * 2;
    unsigned short* K0 = (unsigned short*)wp;  wp += kplane * 2;
    unsigned short* K1 = (unsigned short*)wp;  wp += kplane * 2;
    unsigned short* K2 = (unsigned short*)wp;

    hipMemsetAsync(cnt, 0, (size_t)B * sizeof(int), stream);

    xnsplit_kernel<<<B, 64, 0, stream>>>(x, xn, Xs, xplane, D);
    kinv_kernel<<<(M + 3) / 4, 256, 0, stream>>>(keys, kinv, M, D);
    ksplit_kernel<<<nct * nk, 256, 0, stream>>>(keys, kinv, K0, K1, K2, M, D, nk);

    // XCD-swizzled 1D grid: 64 blocks per ct-group of 8
    int ngrid = 64 * ((nct + 7) / 8);
    gemm_kernel<<<ngrid, 256, 0, stream>>>(Xs, K0, values, cand, cnt,
                                           M, D, nk, nct, xplane, kplane);

    select_kernel<<<B, 256, 0, stream>>>(xn, keys, kinv, values, kptr, out,
                                         cand, cnt, M, D, C);
}

// Round 9
// 675.480 us; speedup vs baseline: 46.1730x; 1.0862x over previous
//
#include <hip/hip_runtime.h>
#include <math.h>

#define BM 128
#define BN 128
#define EPSV 1e-12f
#define NEG_INF_V -1000000000.0f
#define NBINS 2048
#define FBINS 1024
#define FSCALE 5120.0f
#define SCAP 2048
#define CAP 2048
#define SSCAP 1024
#define TAU 0.10f

typedef __attribute__((ext_vector_type(8))) _Float16 f16x8;
typedef __attribute__((ext_vector_type(4))) float f32x4;

union hpack { _Float16 h[8]; f16x8 v; };

// fp32 = 64*(h0 + h1/2048) to ~2^-22 relative; ×64 pre-scale keeps f16 normals
__device__ __forceinline__ void split2(float v, _Float16& h0, _Float16& h1) {
    float sv = v * 64.0f;
    h0 = (_Float16)sv;
    h1 = (_Float16)((sv - (float)h0) * 2048.0f);
}
__device__ __forceinline__ void gload_lds16(const unsigned short* g, const unsigned short* l) {
    __builtin_amdgcn_global_load_lds((const __attribute__((address_space(1))) void*)g,
                                     (__attribute__((address_space(3))) void*)l, 16, 0, 0);
}

// ------- fused: normalize x rows + split into 2 f16 planes (one wave per row) -------
__global__ void xnsplit_kernel(const float* __restrict__ x, float* __restrict__ xn,
                               unsigned short* __restrict__ Xs, size_t xplane, int D) {
    int row = blockIdx.x;
    int lane = threadIdx.x;
    const float4* xr = (const float4*)(x + (size_t)row * D);
    float4* xo = (float4*)(xn + (size_t)row * D);
    int per = (D / 4) / 64;          // D=512 -> 2
    float ss = 0.f;
    float4 v[2];
    for (int i = 0; i < per; ++i) {
        float4 t = xr[lane * per + i];
        v[i] = t;
        ss += t.x * t.x + t.y * t.y + t.z * t.z + t.w * t.w;
    }
    for (int off = 32; off >= 1; off >>= 1) ss += __shfl_xor(ss, off);
    float denom = fmaxf(sqrtf(ss), EPSV);
    float vals[8];
    for (int i = 0; i < per; ++i) {
        float4 t = v[i];
        t.x /= denom; t.y /= denom; t.z /= denom; t.w /= denom;
        xo[lane * per + i] = t;
        vals[i * 4 + 0] = t.x; vals[i * 4 + 1] = t.y;
        vals[i * 4 + 2] = t.z; vals[i * 4 + 3] = t.w;
    }
    hpack p0, p1;
#pragma unroll
    for (int i = 0; i < 8; ++i) split2(vals[i], p0.h[i], p1.h[i]);
    size_t off0 = (size_t)row * D + lane * 8;
    *(f16x8*)(Xs + off0)          = p0.v;
    *(f16x8*)(Xs + xplane + off0) = p1.v;
}

// ------- fused kinv + packed K split (2 f16 planes), one block per col-tile -------
// Packed per (ct, k-chunk) in fragment order with XOR bank swizzle (as r5-r8).
__global__ __launch_bounds__(256)
void kinvsplit_kernel(const float* __restrict__ keys, float* __restrict__ kinv,
                      unsigned short* __restrict__ K0, unsigned short* __restrict__ K1,
                      int M, int D, int nk) {
    const int ct = blockIdx.x;
    const int tid = threadIdx.x;
    const int w = tid >> 6, lane = tid & 63;
    __shared__ float linv[128];

    // phase 1: row norms (wave-per-row, 32 rows/wave), keys read once from HBM
    for (int i = 0; i < 32; ++i) {
        int rl = w * 32 + i;
        int row = ct * 128 + rl;
        if (row >= M) break;
        const float4* kr = (const float4*)(keys + (size_t)row * D);
        float ssum = 0.f;
        int per = (D / 4) / 64;
        for (int p = 0; p < per; ++p) {
            float4 t = kr[lane * per + p];
            ssum += t.x * t.x + t.y * t.y + t.z * t.z + t.w * t.w;
        }
        for (int off = 32; off >= 1; off >>= 1) ssum += __shfl_xor(ssum, off);
        if (lane == 0) {
            float inv = 1.0f / fmaxf(sqrtf(ssum), EPSV);
            linv[rl] = inv;
            kinv[row] = inv;
        }
    }
    __syncthreads();

    // phase 2: split + pack (keys re-read from L2-hot lines)
    for (int t = 0; t < nk; ++t) {
        const size_t blk = ((size_t)ct * nk + t) * 4096;
#pragma unroll
        for (int half = 0; half < 2; ++half) {
            int sig = half * 256 + tid;          // slot 0..511
            int tau = sig >> 6;
            int mp  = (sig >> 2) & 15;
            int qp  = sig & 3;
            int rl  = tau * 16 + mp;
            int row = ct * 128 + rl;
            int qs  = qp ^ (mp & 3);
            hpack p0, p1;
            if (row < M) {
                float inv = linv[rl];
                const float* src = keys + (size_t)row * D + t * 32 + qs * 8;
#pragma unroll
                for (int i = 0; i < 8; ++i) split2(src[i] * inv, p0.h[i], p1.h[i]);
            } else {
#pragma unroll
                for (int i = 0; i < 8; ++i) { p0.h[i] = (_Float16)0.f; p1.h[i] = (_Float16)0.f; }
            }
            size_t off = blk + (size_t)sig * 8;
            *(f16x8*)(K0 + off) = p0.v;
            *(f16x8*)(K1 + off) = p1.v;
        }
    }
}

// ---------------- MFMA GEMM: 128x128 block, 4 waves 2x2, 3 f16 split-products ----------------
// P0 = a0b0, P1 = a0b1 + a1b0 (scale 2^-11). score = (P0 + P1/2048)/4096.
__global__ __launch_bounds__(256, 2)
void gemm_kernel(const unsigned short* __restrict__ Xs,   // 2 planes, stride xplane
                 const unsigned short* __restrict__ Kp,   // 2 packed planes, stride kplane
                 const int* __restrict__ values,
                 int2* __restrict__ cand, int* __restrict__ cnt,
                 int M, int D, int nk, int nct, size_t xplane, size_t kplane) {
    const int l  = blockIdx.x;
    const int ct = (l & 7) + ((l >> 6) << 3);   // XCD swizzle: 8 rt-blocks of a ct share l%8
    const int rt = (l >> 3) & 7;
    if (ct >= nct) return;

    __shared__ unsigned short Bs[2][2 * 4096];   // 2 x 16 KB

    const int tid  = threadIdx.x;
    const int lane = tid & 63;
    const int w    = tid >> 6;
    const int wx   = w >> 1, wy = w & 1;
    const int row0 = rt * BM, col0 = ct * BN;
    const int mq   = lane & 15;
    const int qd   = lane >> 4;
    const int bswz = mq * 32 + ((qd ^ (mq & 3)) << 3);

    f32x4 P0[4][4], P1[4][4];
#pragma unroll
    for (int i = 0; i < 4; ++i)
#pragma unroll
        for (int j = 0; j < 4; ++j) {
            P0[i][j] = (f32x4){0.f, 0.f, 0.f, 0.f};
            P1[i][j] = (f32x4){0.f, 0.f, 0.f, 0.f};
        }

#define STAGE(t_, buf_)                                                          \
    {                                                                            \
        const size_t blk_ = ((size_t)ct * nk + (t_)) * 4096;                     \
        _Pragma("unroll")                                                        \
        for (int i_ = 0; i_ < 4; ++i_) {                                         \
            int s_ = w + i_ * 4;                                                 \
            int sp_ = s_ >> 3, pt_ = s_ & 7;                                     \
            gload_lds16(Kp + (size_t)sp_ * kplane + blk_ + pt_ * 512 + lane * 8, \
                        &Bs[buf_][sp_ * 4096 + pt_ * 512]);                      \
        }                                                                        \
    }

    STAGE(0, 0);

    const unsigned short* arow_base = Xs + (size_t)(row0 + wx * 64 + mq) * D + qd * 8;

    for (int t = 0; t < nk; ++t) {
        const int buf = t & 1;
        __syncthreads();                          // Bs[buf] staged

        // A fragments FIRST (ahead of staging in the vmcnt queue — r8 lesson)
        f16x8 af0[4], af1[4];
#pragma unroll
        for (int ta = 0; ta < 4; ++ta)
            af0[ta] = *(const f16x8*)(arow_base + (size_t)ta * 16 * D + t * 32);
#pragma unroll
        for (int ta = 0; ta < 4; ++ta)
            af1[ta] = *(const f16x8*)(arow_base + xplane + (size_t)ta * 16 * D + t * 32);

        if (t + 1 < nk) STAGE(t + 1, buf ^ 1);    // prefetch behind A in the queue

        {   // group: b-plane1 with a0 -> P1
            f16x8 b1[4];
#pragma unroll
            for (int tb = 0; tb < 4; ++tb)
                b1[tb] = *(const f16x8*)&Bs[buf][4096 + (wy * 4 + tb) * 512 + bswz];
#pragma unroll
            for (int ta = 0; ta < 4; ++ta)
#pragma unroll
                for (int tb = 0; tb < 4; ++tb)
                    P1[ta][tb] = __builtin_amdgcn_mfma_f32_16x16x32_f16(
                        af0[ta], b1[tb], P1[ta][tb], 0, 0, 0);
        }
        {   // group: b-plane0 -> P0 (a0) and P1 (a1)
            f16x8 b0[4];
#pragma unroll
            for (int tb = 0; tb < 4; ++tb)
                b0[tb] = *(const f16x8*)&Bs[buf][(wy * 4 + tb) * 512 + bswz];
#pragma unroll
            for (int ta = 0; ta < 4; ++ta)
#pragma unroll
                for (int tb = 0; tb < 4; ++tb)
                    P0[ta][tb] = __builtin_amdgcn_mfma_f32_16x16x32_f16(
                        af0[ta], b0[tb], P0[ta][tb], 0, 0, 0);
#pragma unroll
            for (int ta = 0; ta < 4; ++ta)
#pragma unroll
                for (int tb = 0; tb < 4; ++tb)
                    P1[ta][tb] = __builtin_amdgcn_mfma_f32_16x16x32_f16(
                        af1[ta], b0[tb], P1[ta][tb], 0, 0, 0);
        }
    }

    // ---- epilogue: combine + candidate collection (C/D: col=lane&15, row=(lane>>4)*4+reg) ----
    int ncol[4]; bool okn[4];
#pragma unroll
    for (int tb = 0; tb < 4; ++tb) {
        int n = col0 + wy * 64 + tb * 16 + mq;
        ncol[tb] = n;
        okn[tb] = (n < M) && (values[n] != -1);
    }
#pragma unroll
    for (int ta = 0; ta < 4; ++ta) {
        int rbase = row0 + wx * 64 + ta * 16 + qd * 4;
#pragma unroll
        for (int tb = 0; tb < 4; ++tb) {
            if (!okn[tb]) continue;
#pragma unroll
            for (int rg = 0; rg < 4; ++rg) {
                float s = (P0[ta][tb][rg] + P1[ta][tb][rg] * 4.8828125e-4f) * 2.44140625e-4f;
                if (s >= TAU) {
                    int r = rbase + rg;
                    int pos = atomicAdd(&cnt[r], 1);
                    if (pos < CAP) cand[(size_t)r * CAP + pos] =
                        make_int2(__float_as_int(s), ncol[tb]);
                }
            }
        }
    }
#undef STAGE
}

// ---------------- selection: fine-histogram filter + small exact rank ----------------
__device__ __forceinline__ int fbin(float s) {
    return (int)fminf((s - TAU) * FSCALE, (float)(FBINS - 1));
}
__device__ __forceinline__ int score_bin(float s) {
    float t = fminf(fmaxf((s + 1.0f) * 1024.0f, 0.0f), 2047.0f);
    return (int)t;
}

__global__ __launch_bounds__(256)
void select_kernel(const float* __restrict__ xn, const float* __restrict__ keys,
                   const float* __restrict__ kinv, const int* __restrict__ values,
                   const int* __restrict__ kptr, float* __restrict__ out,
                   const int2* __restrict__ cand, const int* __restrict__ cnt,
                   int M, int D, int C) {
    const int row = blockIdx.x;
    const int tid = threadIdx.x;
    const int K = *kptr;

    __shared__ float cs[SCAP];
    __shared__ int ci[SCAP];
    __shared__ int hist[NBINS];
    __shared__ float ss[SSCAP];
    __shared__ int si[SSCAP];
    __shared__ float xrow[512];
    __shared__ float accs[32];
    __shared__ int scnt, mcnt, tb;

    const int n0 = cnt[row];
    bool fast = (n0 >= K && n0 <= CAP);
    int m = 0;

    if (tid < 32) accs[tid] = 0.f;
    if (tid == 0) { scnt = 0; mcnt = 0; }

    if (fast) {
        for (int i = tid; i < FBINS; i += 256) hist[i] = 0;
        __syncthreads();
        for (int i = tid; i < n0; i += 256) {
            int2 p = cand[(size_t)row * CAP + i];
            float s = __int_as_float(p.x);
            cs[i] = s; ci[i] = p.y;
            atomicAdd(&hist[fbin(s)], 1);
        }
        __syncthreads();
        if (tid < 64) {
            const int lane = tid;
            int csum = 0;
#pragma unroll
            for (int j = 0; j < FBINS / 64; ++j) csum += hist[lane * (FBINS / 64) + j];
            int sfx = csum;
#pragma unroll
            for (int off = 1; off < 64; off <<= 1) {
                int o = __shfl_down(sfx, off);
                if (lane + off < 64) sfx += o;
            }
            unsigned long long mask = __ballot(sfx >= K);
            int L = 63 - __builtin_clzll(mask);
            int above = (L == 63) ? 0 : __shfl(sfx, L + 1);
            if (lane == L) {
                int c = above;
                int t = L * (FBINS / 64);
                for (int j = FBINS / 64 - 1; j >= 0; --j) {
                    c += hist[L * (FBINS / 64) + j];
                    if (c >= K) { t = L * (FBINS / 64) + j; break; }
                }
                tb = t;
            }
        }
        __syncthreads();
        const int T = tb;
        for (int i = tid; i < n0; i += 256) {
            if (fbin(cs[i]) >= T) {
                int p = atomicAdd(&mcnt, 1);
                if (p < SSCAP) { ss[p] = cs[i]; si[p] = ci[i]; }
            }
        }
        __syncthreads();
        m = mcnt;
        if (m > SSCAP) fast = false;
    }

    if (!fast) {
        for (int d = tid; d < D; d += 256) xrow[d] = xn[(size_t)row * D + d];
        for (int i = tid; i < NBINS; i += 256) hist[i] = 0;
        __syncthreads();
        for (int mm = tid; mm < M; mm += 256) {
            float s;
            if (values[mm] == -1) s = NEG_INF_V;
            else {
                const float4* kr = (const float4*)(keys + (size_t)mm * D);
                float sum = 0.f;
                for (int d4 = 0; d4 < D / 4; ++d4) {
                    float4 t = kr[d4];
                    const float4* xq = (const float4*)&xrow[d4 * 4];
                    sum += t.x * xq->x + t.y * xq->y + t.z * xq->z + t.w * xq->w;
                }
                s = sum * kinv[mm];
            }
            atomicAdd(&hist[score_bin(s)], 1);
        }
        __syncthreads();
        if (tid < 64) {
            const int lane = tid;
            int csum = 0;
#pragma unroll
            for (int j = 0; j < NBINS / 64; ++j) csum += hist[lane * (NBINS / 64) + j];
            int sfx = csum;
#pragma unroll
            for (int off = 1; off < 64; off <<= 1) {
                int o = __shfl_down(sfx, off);
                if (lane + off < 64) sfx += o;
            }
            unsigned long long mask = __ballot(sfx >= K);
            int L = 63 - __builtin_clzll(mask);
            int above = (L == 63) ? 0 : __shfl(sfx, L + 1);
            if (lane == L) {
                int c = above;
                int t = L * (NBINS / 64);
                for (int j = NBINS / 64 - 1; j >= 0; --j) {
                    c += hist[L * (NBINS / 64) + j];
                    if (c >= K) { t = L * (NBINS / 64) + j; break; }
                }
                tb = t;
            }
        }
        __syncthreads();
        const int T = tb;
        for (int mm = tid; mm < M; mm += 256) {
            float s;
            if (values[mm] == -1) s = NEG_INF_V;
            else {
                const float4* kr = (const float4*)(keys + (size_t)mm * D);
                float sum = 0.f;
                for (int d4 = 0; d4 < D / 4; ++d4) {
                    float4 t = kr[d4];
                    const float4* xq = (const float4*)&xrow[d4 * 4];
                    sum += t.x * xq->x + t.y * xq->y + t.z * xq->z + t.w * xq->w;
                }
                s = sum * kinv[mm];
            }
            if (score_bin(s) >= T) {
                int p = atomicAdd(&scnt, 1);
                if (p < SCAP) { cs[p] = s; ci[p] = mm; }
            }
        }
        __syncthreads();
        m = scnt < SCAP ? scnt : SCAP;
    }

    const float* rs = fast ? ss : cs;
    const int* ri = fast ? si : ci;
    for (int i = tid; i < m; i += 256) {
        float s = rs[i];
        int idx = ri[i];
        int rank = 0;
        for (int j = 0; j < m; ++j) {
            float sj = rs[j];
            rank += (sj > s) || (sj == s && ri[j] < idx);
        }
        if (rank < K) {
            int lbl = values[idx];
            if (lbl >= 0) atomicAdd(&accs[lbl], s);
        }
    }
    __syncthreads();
    if (tid < C) out[(size_t)row * C + tid] = accs[tid];
}

extern "C" void kernel_launch(void* const* d_in, const int* in_sizes, int n_in,
                              void* d_out, int out_size, void* d_ws, size_t ws_size,
                              hipStream_t stream) {
    const float* x = (const float*)d_in[0];
    const float* keys = (const float*)d_in[1];
    const int* values = (const int*)d_in[2];
    const int* kptr = (const int*)d_in[3];
    float* out = (float*)d_out;

    const int M = in_sizes[2];            // 60000
    const int D = in_sizes[1] / M;        // 512
    const int B = in_sizes[0] / D;        // 1024
    const int C = out_size / B;           // 10
    const int nk = D / 32;                // 16 k-chunks
    const int nct = (M + BN - 1) / BN;    // 469 col tiles
    const size_t xplane = (size_t)B * D;
    const size_t kplane = (size_t)nct * nk * 4096;

    char* wp = (char*)d_ws;
    float* xn = (float*)wp;                wp += (size_t)B * D * 4;
    float* kinv = (float*)wp;              wp += ((size_t)M * 4 + 255) / 256 * 256;
    int* cnt = (int*)wp;                   wp += (size_t)B * 4;
    int2* cand = (int2*)wp;                wp += (size_t)B * CAP * 8;
    unsigned short* Xs = (unsigned short*)wp;  wp += 2 * xplane * 2;
    unsigned short* K0 = (unsigned short*)wp;  wp += kplane * 2;
    unsigned short* K1 = (unsigned short*)wp;

    hipMemsetAsync(cnt, 0, (size_t)B * sizeof(int), stream);

    xnsplit_kernel<<<B, 64, 0, stream>>>(x, xn, Xs, xplane, D);
    kinvsplit_kernel<<<nct, 256, 0, stream>>>(keys, kinv, K0, K1, M, D, nk);

    // XCD-swizzled 1D grid: 64 blocks per ct-group of 8
    int ngrid = 64 * ((nct + 7) / 8);
    gemm_kernel<<<ngrid, 256, 0, stream>>>(Xs, K0, values, cand, cnt,
                                           M, D, nk, nct, xplane, kplane);

    select_kernel<<<B, 256, 0, stream>>>(xn, keys, kinv, values, kptr, out,
                                         cand, cnt, M, D, C);
}